// Round 5
// baseline (69.400 us; speedup 1.0000x reference)
//
#include <hip/hip_runtime.h>
#include <math.h>

// Problem constants
#define BB   32
#define CC   256
#define HH   56
#define WW   56
#define HID  512
#define RNK  8
#define HWN  (HH * WW)     // 3136
#define HW4  (HWN / 4)     // 784 float4 per (b,c) plane
#define ROW4 (WW / 4)      // 14 float4 per spatial row

__device__ __forceinline__ float gelu_exact(float v) {
    return 0.5f * v * (1.0f + erff(v * 0.70710678118654752f));
}
__device__ __forceinline__ float dot4(float4 a, float4 b) {
    return a.x * b.x + a.y * b.y + a.z * b.z + a.w * b.w;
}
__device__ __forceinline__ float wave_reduce(float d) {
    #pragma unroll
    for (int m = 32; m > 0; m >>= 1) d += __shfl_xor(d, m, 64);
    return d;
}

// ---------------------------------------------------------------------------
// Kernel 1: global average pool.  One 256-thread block per (b,c) plane.
// 103 MB read -> BW-bound, ~15 us floor at the measured ~7 TB/s L3 stream.
// ---------------------------------------------------------------------------
__global__ __launch_bounds__(256) void pool_kernel(const float* __restrict__ x,
                                                   float* __restrict__ y) {
    const int bc  = blockIdx.x;
    const int tid = threadIdx.x;
    const float4* xp = reinterpret_cast<const float4*>(x) + (size_t)bc * HW4;

    float s = 0.0f;
    for (int p = tid; p < HW4; p += 256) {
        float4 v = xp[p];
        s += (v.x + v.y) + (v.z + v.w);
    }
    #pragma unroll
    for (int off = 32; off > 0; off >>= 1) s += __shfl_down(s, off, 64);

    __shared__ float ls[4];
    const int wave = tid >> 6;
    if ((tid & 63) == 0) ls[wave] = s;
    __syncthreads();
    if (tid == 0) {
        float t = (ls[0] + ls[1]) + (ls[2] + ls[3]);
        y[bc] = t * (1.0f / (float)HWN);
    }
}

// ---------------------------------------------------------------------------
// Wave-per-output GEMV: out[b][j] = act(dot(in[b][:K], W[j][:K])).
// One wave per output element; thousands of concurrent waves hide the
// shuffle-reduce latency chain.
// ---------------------------------------------------------------------------
template <int K, int J, bool GELU>
__global__ __launch_bounds__(256) void gemv_kernel(const float* __restrict__ in,
                                                   const float* __restrict__ W,
                                                   float* __restrict__ out) {
    const int lane = threadIdx.x & 63;
    const int wid  = (blockIdx.x * 256 + threadIdx.x) >> 6;  // global wave id
    const int b = wid / J;
    const int j = wid - b * J;
    const float4* wr = reinterpret_cast<const float4*>(W  + (size_t)j * K);
    const float4* ir = reinterpret_cast<const float4*>(in + (size_t)b * K);
    float d;
    if constexpr (K == 256) {
        d = dot4(wr[lane], ir[lane]);
    } else {  // K == 512
        d = dot4(wr[lane], ir[lane]) + dot4(wr[lane + 64], ir[lane + 64]);
    }
    d = wave_reduce(d);
    if (lane == 0) out[(size_t)b * J + j] = GELU ? gelu_exact(d) : d;
}

// Stage 3: A = y'@wA.T and Bm = y'@wB.T fused into one launch.
// ab[b][0..447] = A rows (h-major, RNK inner); ab[b][448..895] = Bm (r*WW+j).
__global__ __launch_bounds__(256) void gemv_ab_kernel(const float* __restrict__ yp,
                                                      const float* __restrict__ wA,
                                                      const float* __restrict__ wB,
                                                      float* __restrict__ ab) {
    const int lane = threadIdx.x & 63;
    const int wid  = (blockIdx.x * 256 + threadIdx.x) >> 6;
    const int b = wid / 896;
    const int j = wid - b * 896;
    const float* W = (j < 448) ? (wA + (size_t)j * CC)
                               : (wB + (size_t)(j - 448) * CC);
    const float4* wr = reinterpret_cast<const float4*>(W);
    const float4* ir = reinterpret_cast<const float4*>(yp + (size_t)b * CC);
    float d = wave_reduce(dot4(wr[lane], ir[lane]));
    if (lane == 0) ab[(size_t)b * 896 + j] = d;
}

// ---------------------------------------------------------------------------
// Kernel 4 (fused): out[b][c][i][j] = sigmoid(sum_r A[b][i][r]*Bm[b][r][j]).
// Recomputes the dot-8 + sigmoid per output float4 instead of staging attn:
// ab is 3.6 KB/batch -> L1-resident with 256x reuse across channels, so the
// extra reads are cache-served and the ~4us of extra VALU hides under the
// 103 MB store stream.  Deletes the attnmap dispatch + one kernel boundary.
// ---------------------------------------------------------------------------
__global__ __launch_bounds__(256) void bcast_map_kernel(const float* __restrict__ ab,
                                                        float4* __restrict__ out) {
    const unsigned total  = (unsigned)BB * CC * HW4;   // 6,422,528 float4
    const unsigned stride = gridDim.x * blockDim.x;
    for (unsigned idx = blockIdx.x * blockDim.x + threadIdx.x; idx < total;
         idx += stride) {
        const unsigned plane = idx / HW4;        // b*C + c
        const unsigned b     = plane / CC;
        const unsigned p4    = idx - plane * HW4;
        const unsigned i     = p4 / ROW4;        // spatial row (float4 never
        const unsigned j0    = (p4 - i * ROW4) * 4;  // crosses a row: 56%4==0)
        const float* A  = ab + (size_t)b * 896 + i * RNK;
        const float* Bm = ab + (size_t)b * 896 + 448 + j0;
        float m0 = 0.f, m1 = 0.f, m2 = 0.f, m3 = 0.f;
        #pragma unroll
        for (int r = 0; r < RNK; ++r) {
            const float a = A[r];
            const float4 bv = *reinterpret_cast<const float4*>(Bm + r * WW);
            m0 += a * bv.x; m1 += a * bv.y; m2 += a * bv.z; m3 += a * bv.w;
        }
        float4 o;
        o.x = 1.0f / (1.0f + expf(-m0));
        o.y = 1.0f / (1.0f + expf(-m1));
        o.z = 1.0f / (1.0f + expf(-m2));
        o.w = 1.0f / (1.0f + expf(-m3));
        out[idx] = o;
    }
}

// ---------------------------------------------------------------------------
extern "C" void kernel_launch(void* const* d_in, const int* in_sizes, int n_in,
                              void* d_out, int out_size, void* d_ws, size_t ws_size,
                              hipStream_t stream) {
    const float* x  = (const float*)d_in[0];
    const float* w1 = (const float*)d_in[1];
    const float* w2 = (const float*)d_in[2];
    const float* wA = (const float*)d_in[3];
    const float* wB = (const float*)d_in[4];
    float* out = (float*)d_out;

    // ws layout (floats): y[B*C] | h[B*HID] | yp[B*C] | ab[B*896]
    float* y  = (float*)d_ws;
    float* h  = y  + BB * CC;          // 8192
    float* yp = h  + BB * HID;         // 16384
    float* ab = yp + BB * CC;          // 8192   (+28672 = 61440 floats, 246 KB)

    pool_kernel<<<BB * CC, 256, 0, stream>>>(x, y);
    gemv_kernel<CC, HID, true><<<(BB * HID) / 4, 256, 0, stream>>>(y, w1, h);
    gemv_kernel<HID, CC, true><<<(BB * CC) / 4, 256, 0, stream>>>(h, w2, yp);
    gemv_ab_kernel<<<(BB * 896) / 4, 256, 0, stream>>>(yp, wA, wB, ab);
    bcast_map_kernel<<<2048, 256, 0, stream>>>(ab, reinterpret_cast<float4*>(out));
}